// Round 26
// baseline (240.388 us; speedup 1.0000x reference)
//
#include <hip/hip_runtime.h>
#include <hip/hip_fp16.h>

#define N_NODES 100000
#define E_EDGES 1600000
#define FDIM 64
#define G_GRAPHS 128
#define OUTD 32
#define NPB 512       // nodes per bucket (power of 2)
#define NPB_SH 9
#define KBUK ((N_NODES + NPB - 1) / NPB)   // 196 (<= 256)
#define CAPB 10240    // fixed edge capacity per bucket region
#define SEB 4096      // edges per block in bucket scatter
#define SEBLK ((E_EDGES + SEB - 1) / SEB)  // 391
#define GCH 16        // chunks per graph in global pooling

__device__ __forceinline__ __half2 u2h(unsigned int u) {
    union { unsigned int i; __half2 h; } c; c.i = u; return c.h;
}
__device__ __forceinline__ unsigned int h2u(__half2 h) {
    union { __half2 h; unsigned int i; } c; c.h = h; return c.i;
}
__device__ __forceinline__ __half2 sxh2(__half2 v, int off) {
    return u2h((unsigned int)__shfl_xor((int)h2u(v), off));
}
// packed f16 ops via VOP3P inline asm (ROCm fp16 header lacks __half2 min/max)
__device__ __forceinline__ __half2 h2min(__half2 a, __half2 b) {
    unsigned int r, x = h2u(a), y = h2u(b);
    asm("v_pk_min_f16 %0, %1, %2" : "=v"(r) : "v"(x), "v"(y));
    return u2h(r);
}
__device__ __forceinline__ __half2 h2max(__half2 a, __half2 b) {
    unsigned int r, x = h2u(a), y = h2u(b);
    asm("v_pk_max_f16 %0, %1, %2" : "=v"(r) : "v"(x), "v"(y));
    return u2h(r);
}
__device__ __forceinline__ __half2 h2add(__half2 a, __half2 b) {
    unsigned int r, x = h2u(a), y = h2u(b);
    asm("v_pk_add_f16 %0, %1, %2" : "=v"(r) : "v"(x), "v"(y));
    return u2h(r);
}
// f32 += f16x2 . f16x2 (packed dot product, f32 accumulate)
__device__ __forceinline__ float dot2(float acc, unsigned int a, unsigned int b) {
    float r;
    asm("v_dot2_f32_f16 %0, %1, %2, %3" : "=v"(r) : "v"(a), "v"(b), "v"(acc));
    return r;
}

// ---------------- CSR build (bucketed, fixed-capacity regions) ----------------

// batch is sorted -> graph starts at value changes; also init bucket cursors.
__global__ __launch_bounds__(256) void bound_kernel(const int* __restrict__ batch,
                                                    int* __restrict__ gstart,
                                                    int* __restrict__ bucketCursor) {
    int i = blockIdx.x * 256 + threadIdx.x;
    if (blockIdx.x == 0 && threadIdx.x < KBUK)
        bucketCursor[threadIdx.x * 16] = threadIdx.x * CAPB;
    if (i >= N_NODES) return;
    if (i == 0) {
        gstart[batch[0]] = 0;
    } else {
        int b = batch[i], pb = batch[i - 1];
        if (b != pb) gstart[b] = i;
    }
}

__global__ __launch_bounds__(256) void bscatter_kernel(const int* __restrict__ src,
                                                       const int* __restrict__ dst,
                                                       int* __restrict__ bucketCursor,
                                                       int* __restrict__ ebuf) {
    __shared__ int h[KBUK], resbase[KBUK], lcur[KBUK];
    for (int i = threadIdx.x; i < KBUK; i += 256) { h[i] = 0; lcur[i] = 0; }
    __syncthreads();
    const int base = blockIdx.x * SEB;
#pragma unroll
    for (int i = 0; i < 16; ++i) {
        int e = base + i * 256 + threadIdx.x;
        if (e < E_EDGES) atomicAdd(&h[dst[e] >> NPB_SH], 1);
    }
    __syncthreads();
    for (int i = threadIdx.x; i < KBUK; i += 256)
        resbase[i] = h[i] ? atomicAdd(&bucketCursor[i * 16], h[i]) : 0;
    __syncthreads();
#pragma unroll
    for (int i = 0; i < 16; ++i) {
        int e = base + i * 256 + threadIdx.x;
        if (e < E_EDGES) {
            int d = dst[e];
            int b = d >> NPB_SH;
            int pos = resbase[b] + atomicAdd(&lcur[b], 1);
            ebuf[pos] = (src[e] << NPB_SH) | (d & (NPB - 1));
        }
    }
}

__global__ __launch_bounds__(256) void bscan_kernel(const int* __restrict__ bucketCursor,
                                                    int* __restrict__ bucketStart,
                                                    int* __restrict__ offsets) {
    __shared__ int s[256];
    const int tid = threadIdx.x;
    int v = (tid < KBUK) ? (bucketCursor[tid * 16] - tid * CAPB) : 0;
    s[tid] = v;
    __syncthreads();
    for (int off = 1; off < 256; off <<= 1) {
        int t = 0;
        if (tid >= off) t = s[tid - off];
        __syncthreads();
        if (tid >= off) s[tid] += t;
        __syncthreads();
    }
    int excl = s[tid] - v;
    if (tid < KBUK) bucketStart[tid] = excl;
    if (tid == 0) { bucketStart[KBUK] = E_EDGES; offsets[N_NODES] = E_EDGES; }
}

// per-bucket counting sort -> offsets[] + srcSorted[] (prescaled by 16 = uint2-row)
__global__ __launch_bounds__(256) void bsort_kernel(const int* __restrict__ ebuf,
                                                    const int* __restrict__ bucketStart,
                                                    int* __restrict__ offsets,
                                                    int* __restrict__ srcSorted) {
    __shared__ int cnt[NPB];
    __shared__ int cur[NPB];
    __shared__ int wsum[4];
    const int b = blockIdx.x;
    const int tid = threadIdx.x;
    const int rbase = b * CAPB;
    const int ebase = bucketStart[b];
    const int cb = bucketStart[b + 1] - ebase;
    const int nbase = b * NPB;
    cnt[tid] = 0; cnt[tid + 256] = 0;
    __syncthreads();
    for (int e = tid; e < cb; e += 256)
        atomicAdd(&cnt[ebuf[rbase + e] & (NPB - 1)], 1);
    __syncthreads();
    int v0 = cnt[2 * tid], v1 = cnt[2 * tid + 1];
    int s = v0 + v1;
    const int lane = tid & 63, wv = tid >> 6;
    int incl = s;
#pragma unroll
    for (int off = 1; off < 64; off <<= 1) {
        int o = __shfl_up(incl, off);
        if (lane >= off) incl += o;
    }
    if (lane == 63) wsum[wv] = incl;
    __syncthreads();
    int wpre = 0;
#pragma unroll
    for (int w = 0; w < 4; ++w) wpre += (w < wv) ? wsum[w] : 0;
    int excl = wpre + incl - s;
    cur[2 * tid] = excl; cur[2 * tid + 1] = excl + v0;
    int n0 = nbase + 2 * tid;
    if (n0 < N_NODES) offsets[n0] = ebase + excl;
    if (n0 + 1 < N_NODES) offsets[n0 + 1] = ebase + excl + v0;
    __syncthreads();
    for (int e = tid; e < cb; e += 256) {
        int u = ebuf[rbase + e];
        int pos = ebase + atomicAdd(&cur[u & (NPB - 1)], 1);
        srcSorted[pos] = (u >> NPB_SH) << 4;  // prescaled row offset (uint2 units)
    }
}

// ---------------- linear (4x4 register-tiled, dot2, optional dual W) ----------------
// 256 threads = 16 node-quads x 16 feature-quads; block = 64 nodes.
// h AND W tiles in LDS as f16; inner loop = chained v_dot2_f32_f16.
// F32IN: input is f32 (layer 0's x) -> cvt on stage; else f16 direct copy.
// Trunk (outC) stored f16 (round-25: matmul input is f16-rounded anyway).
// #pragma unroll 1 caps register pressure (round-10 spill lesson).
// In-place safe (outC == inH): block stages its own rows before the barrier.

template <bool DUAL, bool F32IN>
__global__ __launch_bounds__(256) void lin_kernel(const float* __restrict__ inF,
                                                  const __half* __restrict__ inH,
                                                  const float* __restrict__ Wm,
                                                  const float* __restrict__ bm,
                                                  const float* __restrict__ Wc,
                                                  const float* __restrict__ bc,
                                                  __half* __restrict__ outMsg,
                                                  __half* __restrict__ outC) {
    extern __shared__ uint2 shu[];
    uint2* shH  = shu;          // 1024
    uint2* shWm = shu + 1024;   // 1024
    uint2* shWc = shu + 2048;   // dual only
    const int tid = threadIdx.x;
    const int base = blockIdx.x * 64;
#pragma unroll
    for (int i = 0; i < 4; ++i) {
        int j = tid + i * 256;                 // 4-elem unit index in 64x64 tile
        int row = j >> 4, col = j & 15;
        int swz = row * 16 + (col ^ ((row >> 2) & 7));
        if (base + row < N_NODES) {
            uint2 ph;
            if (F32IN) {
                float4 hv = ((const float4*)inF)[(size_t)base * 16 + j];
                ph.x = h2u(__floats2half2_rn(hv.x, hv.y));
                ph.y = h2u(__floats2half2_rn(hv.z, hv.w));
            } else {
                ph = ((const uint2*)inH)[(size_t)base * 16 + j];
            }
            shH[swz] = ph;
        }
        float4 wm = ((const float4*)Wm)[j];
        uint2 pm;
        pm.x = h2u(__floats2half2_rn(wm.x, wm.y));
        pm.y = h2u(__floats2half2_rn(wm.z, wm.w));
        shWm[swz] = pm;
        if (DUAL) {
            float4 wc = ((const float4*)Wc)[j];
            uint2 pc;
            pc.x = h2u(__floats2half2_rn(wc.x, wc.y));
            pc.y = h2u(__floats2half2_rn(wc.z, wc.w));
            shWc[swz] = pc;
        }
    }
    __syncthreads();
    const int fj = tid & 15, ni = tid >> 4;
    float accM[4][4] = {{0}}, accC[4][4] = {{0}};
    const int hs = ni & 7;
    const int ws = fj & 7;
#pragma unroll 1
    for (int kk = 0; kk < 16; ++kk) {
        const int hk = kk ^ hs, wk = kk ^ ws;
        uint2 h0 = shH[(4 * ni + 0) * 16 + hk];
        uint2 h1 = shH[(4 * ni + 1) * 16 + hk];
        uint2 h2 = shH[(4 * ni + 2) * 16 + hk];
        uint2 h3 = shH[(4 * ni + 3) * 16 + hk];
#pragma unroll
        for (int j = 0; j < 4; ++j) {
            uint2 wu = shWm[(4 * fj + j) * 16 + wk];
            accM[0][j] = dot2(dot2(accM[0][j], h0.x, wu.x), h0.y, wu.y);
            accM[1][j] = dot2(dot2(accM[1][j], h1.x, wu.x), h1.y, wu.y);
            accM[2][j] = dot2(dot2(accM[2][j], h2.x, wu.x), h2.y, wu.y);
            accM[3][j] = dot2(dot2(accM[3][j], h3.x, wu.x), h3.y, wu.y);
            if (DUAL) {
                uint2 cu = shWc[(4 * fj + j) * 16 + wk];
                accC[0][j] = dot2(dot2(accC[0][j], h0.x, cu.x), h0.y, cu.y);
                accC[1][j] = dot2(dot2(accC[1][j], h1.x, cu.x), h1.y, cu.y);
                accC[2][j] = dot2(dot2(accC[2][j], h2.x, cu.x), h2.y, cu.y);
                accC[3][j] = dot2(dot2(accC[3][j], h3.x, cu.x), h3.y, cu.y);
            }
        }
    }
    float4 bm4 = *(const float4*)(bm + 4 * fj);
    float4 bc4 = DUAL ? *(const float4*)(bc + 4 * fj) : make_float4(0, 0, 0, 0);
#pragma unroll
    for (int r = 0; r < 4; ++r) {
        int node = base + 4 * ni + r;
        if (node < N_NODES) {
            uint2 st;
            st.x = h2u(__floats2half2_rn(accM[r][0] + bm4.x, accM[r][1] + bm4.y));
            st.y = h2u(__floats2half2_rn(accM[r][2] + bm4.z, accM[r][3] + bm4.w));
            *(uint2*)(outMsg + (size_t)node * 64 + 4 * fj) = st;
            if (DUAL) {
                uint2 ct;
                ct.x = h2u(__floats2half2_rn(accC[r][0] + bc4.x, accC[r][1] + bc4.y));
                ct.y = h2u(__floats2half2_rn(accC[r][2] + bc4.z, accC[r][3] + bc4.w));
                *(uint2*)(outC + (size_t)node * 64 + 4 * fj) = ct;
            }
        }
    }
}

// ---------------- per-node adaptive-relu aggregation (register-held, no LDS) ----
// wave per node; lane = (edge group g = lane>>4, feature quad fq = lane&15).
// deg>=16: ALL 8 gathers issued before any stat op (round-24 MLP lesson).
// h trunk stored f16; update computed in f32, rounded once.

__global__ __launch_bounds__(256) void agg_kernel(const __half* __restrict__ msgH,
                                                  const int* __restrict__ offsets,
                                                  const int* __restrict__ srcSorted,
                                                  const float* __restrict__ tptr,
                                                  const float* __restrict__ Wp,
                                                  const float* __restrict__ bp,
                                                  __half* __restrict__ hbuf) {
    const int lane = threadIdx.x & 63;
    const int g = lane >> 4;
    const int fq = lane & 15;
    const int node = blockIdx.x * 4 + (threadIdx.x >> 6);
    if (node >= N_NODES) return;
    const int start = offsets[node], end = offsets[node + 1];
    const int deg = end - start;
    const uint2* mq = (const uint2*)msgH + fq;  // row stride = 16 uint2 (128 B)
    const float INF = 65504.f;  // f16 max
    __half2 mnA = __float2half2_rn(INF),  mnB = __float2half2_rn(INF);
    __half2 mxA = __float2half2_rn(-INF), mxB = __float2half2_rn(-INF);
    __half2 smA = __float2half2_rn(0.f),  smB = __float2half2_rn(0.f);

#define ACCU(u) { __half2 a_ = u2h((u).x), b_ = u2h((u).y); \
    mnA = h2min(mnA, a_); mxA = h2max(mxA, a_); smA = h2add(smA, a_); \
    mnB = h2min(mnB, b_); mxB = h2max(mxB, b_); smB = h2add(smB, b_); }

    // register-held first 32 slots
    uint2 u0, u1, u2, u3, v0, v1, v2, v3;
    bool okU0 = false, okU1 = false, okU2 = false, okU3 = false;
    bool okV0 = false, okV1 = false, okV2 = false, okV3 = false;

    if (deg >= 16) {
        // ---- issue ALL loads first (8 gathers in flight) ----
        int i0 = start + g;
        int s0 = srcSorted[i0], s1 = srcSorted[i0 + 4];
        int s2 = srcSorted[i0 + 8], s3 = srcSorted[i0 + 12];
        u0 = mq[(size_t)s0]; u1 = mq[(size_t)s1];
        u2 = mq[(size_t)s2]; u3 = mq[(size_t)s3];
        okU0 = okU1 = okU2 = okU3 = true;
        int j0 = start + 16 + g, j1 = j0 + 4, j2 = j0 + 8, j3 = j0 + 12;
        okV0 = j0 < end; okV1 = j1 < end; okV2 = j2 < end; okV3 = j3 < end;
        int t0 = 0, t1 = 0, t2 = 0, t3 = 0;
        if (okV0) t0 = srcSorted[j0];
        if (okV1) t1 = srcSorted[j1];
        if (okV2) t2 = srcSorted[j2];
        if (okV3) t3 = srcSorted[j3];
        if (okV0) v0 = mq[(size_t)t0];
        if (okV1) v1 = mq[(size_t)t1];
        if (okV2) v2 = mq[(size_t)t2];
        if (okV3) v3 = mq[(size_t)t3];
        // ---- then drain into stats ----
        ACCU(u0) ACCU(u1) ACCU(u2) ACCU(u3)
        if (okV0) ACCU(v0)
        if (okV1) ACCU(v1)
        if (okV2) ACCU(v2)
        if (okV3) ACCU(v3)
        if (deg > 32) {   // overflow: stats only (re-gathered in pass 2)
            for (int e = start + 32; e < end; e += 16) {
                int i0e = e + g, i1e = i0e + 4, i2e = i0e + 8, i3e = i0e + 12;
                bool ok0 = i0e < end, ok1 = i1e < end, ok2 = i2e < end, ok3 = i3e < end;
                int s0e = 0, s1e = 0, s2e = 0, s3e = 0;
                if (ok0) s0e = srcSorted[i0e];
                if (ok1) s1e = srcSorted[i1e];
                if (ok2) s2e = srcSorted[i2e];
                if (ok3) s3e = srcSorted[i3e];
                uint2 w0, w1, w2, w3;
                if (ok0) w0 = mq[(size_t)s0e];
                if (ok1) w1 = mq[(size_t)s1e];
                if (ok2) w2 = mq[(size_t)s2e];
                if (ok3) w3 = mq[(size_t)s3e];
                if (ok0) ACCU(w0)
                if (ok1) ACCU(w1)
                if (ok2) ACCU(w2)
                if (ok3) ACCU(w3)
            }
        }
    } else {   // deg < 16: single masked load
        int i0 = start + g, i1 = i0 + 4, i2 = i0 + 8, i3 = i0 + 12;
        okU0 = i0 < end; okU1 = i1 < end; okU2 = i2 < end; okU3 = i3 < end;
        int s0 = 0, s1 = 0, s2 = 0, s3 = 0;
        if (okU0) s0 = srcSorted[i0];
        if (okU1) s1 = srcSorted[i1];
        if (okU2) s2 = srcSorted[i2];
        if (okU3) s3 = srcSorted[i3];
        if (okU0) u0 = mq[(size_t)s0];
        if (okU1) u1 = mq[(size_t)s1];
        if (okU2) u2 = mq[(size_t)s2];
        if (okU3) u3 = mq[(size_t)s3];
        if (okU0) ACCU(u0)
        if (okU1) ACCU(u1)
        if (okU2) ACCU(u2)
        if (okU3) ACCU(u3)
    }
#pragma unroll
    for (int off = 16; off <= 32; off <<= 1) {
        mnA = h2min(mnA, sxh2(mnA, off)); mnB = h2min(mnB, sxh2(mnB, off));
        mxA = h2max(mxA, sxh2(mxA, off)); mxB = h2max(mxB, sxh2(mxB, off));
        smA = h2add(smA, sxh2(smA, off)); smB = h2add(smB, sxh2(smB, off));
    }
    float mn0 = __low2float(mnA), mn1 = __high2float(mnA);
    float mn2 = __low2float(mnB), mn3 = __high2float(mnB);
    float mx0 = __low2float(mxA), mx1 = __high2float(mxA);
    float mx2 = __low2float(mxB), mx3 = __high2float(mxB);
    float4 tv = *(const float4*)(tptr + 4 * fq);
    tv.x = fminf(fmaxf(tv.x, 0.f), 1.f); tv.y = fminf(fmaxf(tv.y, 0.f), 1.f);
    tv.z = fminf(fmaxf(tv.z, 0.f), 1.f); tv.w = fminf(fmaxf(tv.w, 0.f), 1.f);
    float b0 = tv.x * mx0 + (1.f - tv.x) * mn0;
    float b1 = tv.y * mx1 + (1.f - tv.y) * mn1;
    float b2 = tv.z * mx2 + (1.f - tv.z) * mn2;
    float b3 = tv.w * mx3 + (1.f - tv.w) * mn3;
    __half2 biasA = __floats2half2_rn(b0, b1);
    __half2 biasB = __floats2half2_rn(b2, b3);
    float fb0 = __low2float(biasA), fb1 = __high2float(biasA);
    float fb2 = __low2float(biasB), fb3 = __high2float(biasB);
    __half2 rsA = __float2half2_rn(0.f), rsB = __float2half2_rn(0.f);

#define RACCU(u) { __half2 a_ = u2h((u).x), b_ = u2h((u).y); \
    rsA = h2add(rsA, h2max(a_, biasA)); \
    rsB = h2add(rsB, h2max(b_, biasB)); }

    // pass 2: from registers (flags mirror pass 1)
    if (okU0) RACCU(u0)
    if (okU1) RACCU(u1)
    if (okU2) RACCU(u2)
    if (okU3) RACCU(u3)
    if (okV0) RACCU(v0)
    if (okV1) RACCU(v1)
    if (okV2) RACCU(v2)
    if (okV3) RACCU(v3)
    if (deg > 32) {   // rare overflow: re-gather
        for (int e = start + 32; e < end; e += 16) {
            int i0e = e + g, i1e = i0e + 4, i2e = i0e + 8, i3e = i0e + 12;
            bool ok0 = i0e < end, ok1 = i1e < end, ok2 = i2e < end, ok3 = i3e < end;
            int s0e = 0, s1e = 0, s2e = 0, s3e = 0;
            if (ok0) s0e = srcSorted[i0e];
            if (ok1) s1e = srcSorted[i1e];
            if (ok2) s2e = srcSorted[i2e];
            if (ok3) s3e = srcSorted[i3e];
            uint2 w0, w1, w2, w3;
            if (ok0) w0 = mq[(size_t)s0e];
            if (ok1) w1 = mq[(size_t)s1e];
            if (ok2) w2 = mq[(size_t)s2e];
            if (ok3) w3 = mq[(size_t)s3e];
            if (ok0) RACCU(w0)
            if (ok1) RACCU(w1)
            if (ok2) RACCU(w2)
            if (ok3) RACCU(w3)
        }
    }
#pragma unroll
    for (int off = 16; off <= 32; off <<= 1) {
        rsA = h2add(rsA, sxh2(rsA, off));
        rsB = h2add(rsB, sxh2(rsB, off));
    }
    if (g == 0) {
        float cnt = (float)deg;
        float w0 = Wp[0], w1 = Wp[1], w2 = Wp[2], w3 = Wp[3], w4 = Wp[4], bp0 = bp[0];
        float rs0 = __low2float(rsA) - cnt * fb0;
        float rs1 = __high2float(rsA) - cnt * fb1;
        float rs2 = __low2float(rsB) - cnt * fb2;
        float rs3 = __high2float(rsB) - cnt * fb3;
        float sm0 = __low2float(smA), sm1 = __high2float(smA);
        float sm2 = __low2float(smB), sm3 = __high2float(smB);
        uint2* hp = (uint2*)(hbuf + (size_t)node * 64 + 4 * fq);
        uint2 hcur = *hp;
        __half2 hlo = u2h(hcur.x), hhi = u2h(hcur.y);
        float h0 = __low2float(hlo) + w0 * cnt + w1 * mn0 + w2 * mx0 + w3 * rs0 + w4 * sm0 + bp0;
        float h1 = __high2float(hlo) + w0 * cnt + w1 * mn1 + w2 * mx1 + w3 * rs1 + w4 * sm1 + bp0;
        float h2 = __low2float(hhi) + w0 * cnt + w1 * mn2 + w2 * mx2 + w3 * rs2 + w4 * sm2 + bp0;
        float h3 = __high2float(hhi) + w0 * cnt + w1 * mn3 + w2 * mx3 + w3 * rs3 + w4 * sm3 + bp0;
        hcur.x = h2u(__floats2half2_rn(h0, h1));
        hcur.y = h2u(__floats2half2_rn(h2, h3));
        *hp = hcur;
    }
#undef ACCU
#undef RACCU
}

// ---------------- global pooling (4-phase; vectorized __half2 loads) ----------

// A: partial min/max/sum; lane = (feature pair p = tid&31, row-walker r = tid>>5)
__global__ __launch_bounds__(256) void gaggA_kernel(const __half* __restrict__ msgH,
                                                    const int* __restrict__ gstart,
                                                    float* __restrict__ pmn,
                                                    float* __restrict__ pmx,
                                                    float* __restrict__ psm) {
    const int bid = blockIdx.x;
    const int g = bid >> 4, c = bid & (GCH - 1);
    const int s = gstart[g];
    const int e = (g == G_GRAPHS - 1) ? N_NODES : gstart[g + 1];
    const int clen = (e - s + GCH - 1) / GCH;
    const int cs = s + c * clen;
    const int ce = (cs + clen < e) ? (cs + clen) : e;
    const int p = threadIdx.x & 31, r = threadIdx.x >> 5;
    const float INF = __builtin_inff();
    float mn0 = INF, mn1 = INF, mx0 = -INF, mx1 = -INF, sm0 = 0.f, sm1 = 0.f;
    for (int i = cs + r; i < ce; i += 8) {
        unsigned int u = *(const unsigned int*)(msgH + (size_t)i * 64 + 2 * p);
        __half2 h = u2h(u);
        float v0 = __low2float(h), v1 = __high2float(h);
        mn0 = fminf(mn0, v0); mx0 = fmaxf(mx0, v0); sm0 += v0;
        mn1 = fminf(mn1, v1); mx1 = fmaxf(mx1, v1); sm1 += v1;
    }
    __shared__ float smn[8][64], smx[8][64], ssm[8][64];
    smn[r][2 * p] = mn0; smn[r][2 * p + 1] = mn1;
    smx[r][2 * p] = mx0; smx[r][2 * p + 1] = mx1;
    ssm[r][2 * p] = sm0; ssm[r][2 * p + 1] = sm1;
    __syncthreads();
    if (threadIdx.x < 64) {
        int f = threadIdx.x;
        float mn = smn[0][f], mx = smx[0][f], sm = ssm[0][f];
#pragma unroll
        for (int k = 1; k < 8; ++k) {
            mn = fminf(mn, smn[k][f]); mx = fmaxf(mx, smx[k][f]); sm += ssm[k][f];
        }
        pmn[bid * 64 + f] = mn; pmx[bid * 64 + f] = mx; psm[bid * 64 + f] = sm;
    }
}

__global__ __launch_bounds__(64) void gaggB_kernel(const float* __restrict__ pmn,
                                                   const float* __restrict__ pmx,
                                                   const float* __restrict__ psm,
                                                   const float* __restrict__ gt,
                                                   float* __restrict__ gMn,
                                                   float* __restrict__ gMx,
                                                   float* __restrict__ gSm,
                                                   float* __restrict__ gBias) {
    const int g = blockIdx.x, f = threadIdx.x;
    float mn = __builtin_inff(), mx = -__builtin_inff(), sm = 0.f;
#pragma unroll
    for (int c = 0; c < GCH; ++c) {
        int i = (g * GCH + c) * 64 + f;
        mn = fminf(mn, pmn[i]); mx = fmaxf(mx, pmx[i]); sm += psm[i];
    }
    float tv = fminf(fmaxf(gt[f], 0.f), 1.f);
    gMn[g * 64 + f] = mn; gMx[g * 64 + f] = mx; gSm[g * 64 + f] = sm;
    gBias[g * 64 + f] = tv * mx + (1.f - tv) * mn;
}

// C: partial relu sums (vectorized __half2 loads)
__global__ __launch_bounds__(256) void gaggC_kernel(const __half* __restrict__ msgH,
                                                    const int* __restrict__ gstart,
                                                    const float* __restrict__ gBias,
                                                    float* __restrict__ prs) {
    const int bid = blockIdx.x;
    const int g = bid >> 4, c = bid & (GCH - 1);
    const int s = gstart[g];
    const int e = (g == G_GRAPHS - 1) ? N_NODES : gstart[g + 1];
    const int clen = (e - s + GCH - 1) / GCH;
    const int cs = s + c * clen;
    const int ce = (cs + clen < e) ? (cs + clen) : e;
    const int p = threadIdx.x & 31, r = threadIdx.x >> 5;
    const float bias0 = gBias[g * 64 + 2 * p];
    const float bias1 = gBias[g * 64 + 2 * p + 1];
    float rs0 = 0.f, rs1 = 0.f;
    for (int i = cs + r; i < ce; i += 8) {
        unsigned int u = *(const unsigned int*)(msgH + (size_t)i * 64 + 2 * p);
        __half2 h = u2h(u);
        rs0 += fmaxf(__low2float(h) - bias0, 0.f);
        rs1 += fmaxf(__high2float(h) - bias1, 0.f);
    }
    __shared__ float srs[8][64];
    srs[r][2 * p] = rs0; srs[r][2 * p + 1] = rs1;
    __syncthreads();
    if (threadIdx.x < 64) {
        int f = threadIdx.x;
        float rs = srs[0][f];
#pragma unroll
        for (int k = 1; k < 8; ++k) rs += srs[k][f];
        prs[bid * 64 + f] = rs;
    }
}

__global__ __launch_bounds__(64) void gaggD_kernel(const float* __restrict__ prs,
                                                   const int* __restrict__ gstart,
                                                   const float* __restrict__ gMn,
                                                   const float* __restrict__ gMx,
                                                   const float* __restrict__ gSm,
                                                   const float* __restrict__ gWp,
                                                   const float* __restrict__ gbp,
                                                   const float* __restrict__ Wout,
                                                   const float* __restrict__ bout,
                                                   float* __restrict__ out) {
    const int g = blockIdx.x, f = threadIdx.x;
    float rs = 0.f;
#pragma unroll
    for (int c = 0; c < GCH; ++c) rs += prs[(g * GCH + c) * 64 + f];
    const int s = gstart[g];
    const int e = (g == G_GRAPHS - 1) ? N_NODES : gstart[g + 1];
    float cnt = (float)(e - s);
    __shared__ float emb[64];
    emb[f] = gWp[0] * cnt + gWp[1] * gMn[g * 64 + f] + gWp[2] * gMx[g * 64 + f] +
             gWp[3] * rs + gWp[4] * gSm[g * 64 + f] + gbp[0];
    __syncthreads();
    if (f < OUTD) {
        float a = bout[f];
        const float* wr = Wout + f * 64;
#pragma unroll
        for (int k = 0; k < 64; ++k) a = fmaf(emb[k], wr[k], a);
        out[g * OUTD + f] = a;
    }
}

// ---------------- launch ----------------

extern "C" void kernel_launch(void* const* d_in, const int* in_sizes, int n_in,
                              void* d_out, int out_size, void* d_ws, size_t ws_size,
                              hipStream_t stream) {
    const float* x     = (const float*)d_in[0];
    const int*   ei    = (const int*)d_in[1];
    const int*   batch = (const int*)d_in[2];
    const float* Wlin  = (const float*)d_in[3];
    const float* blin  = (const float*)d_in[4];
    const float* t     = (const float*)d_in[5];
    const float* Wproj = (const float*)d_in[6];
    const float* bproj = (const float*)d_in[7];
    const float* Wc    = (const float*)d_in[8];
    const float* bc    = (const float*)d_in[9];
    const float* gWlin = (const float*)d_in[10];
    const float* gblin = (const float*)d_in[11];
    const float* gt    = (const float*)d_in[12];
    const float* gWproj= (const float*)d_in[13];
    const float* gbproj= (const float*)d_in[14];
    const float* Wout  = (const float*)d_in[15];
    const float* bout  = (const float*)d_in[16];
    float* out = (float*)d_out;

    const int* src = ei;
    const int* dst = ei + E_EDGES;

    // workspace layout
    char* p = (char*)d_ws;
    __half* bufH  = (__half*)p; p += (size_t)N_NODES * FDIM * sizeof(__half);
    __half* msgH  = (__half*)p; p += (size_t)N_NODES * FDIM * sizeof(__half);
    int* ebuf     = (int*)p;   p += (size_t)KBUK * CAPB * sizeof(int);
    int* offsets  = (int*)p;   p += (size_t)(N_NODES + 1) * sizeof(int);
    int* gstart   = (int*)p;   p += (size_t)G_GRAPHS * sizeof(int);
    int* bucketStart  = (int*)p; p += (size_t)(KBUK + 1) * sizeof(int);
    int* bucketCursor = (int*)p; p += (size_t)KBUK * 16 * sizeof(int);
    int* srcSorted= (int*)p;   p += (size_t)E_EDGES * sizeof(int);
    float* pmn = (float*)p;    p += (size_t)G_GRAPHS * GCH * 64 * sizeof(float);
    float* pmx = (float*)p;    p += (size_t)G_GRAPHS * GCH * 64 * sizeof(float);
    float* psm = (float*)p;    p += (size_t)G_GRAPHS * GCH * 64 * sizeof(float);
    float* prs = (float*)p;    p += (size_t)G_GRAPHS * GCH * 64 * sizeof(float);
    float* gMn = (float*)p;    p += (size_t)G_GRAPHS * 64 * sizeof(float);
    float* gMx = (float*)p;    p += (size_t)G_GRAPHS * 64 * sizeof(float);
    float* gSm = (float*)p;    p += (size_t)G_GRAPHS * 64 * sizeof(float);
    float* gBias = (float*)p;  p += (size_t)G_GRAPHS * 64 * sizeof(float);

    const int NB = (N_NODES + 255) / 256;
    bound_kernel<<<NB, 256, 0, stream>>>(batch, gstart, bucketCursor);
    bscatter_kernel<<<SEBLK, 256, 0, stream>>>(src, dst, bucketCursor, ebuf);
    bscan_kernel<<<1, 256, 0, stream>>>(bucketCursor, bucketStart, offsets);
    bsort_kernel<<<KBUK, 256, 0, stream>>>(ebuf, bucketStart, offsets, srcSorted);

    const int LB = (N_NODES + 63) / 64;
    const int AB = (N_NODES + 3) / 4;
    const size_t LDS_DUAL = 3 * 1024 * sizeof(uint2);    // 24 KB
    const size_t LDS_SINGLE = 2 * 1024 * sizeof(uint2);  // 16 KB

    // layer 0: msg (f16) + combine (f16 trunk) fused, from x (f32)
    lin_kernel<true, true><<<LB, 256, LDS_DUAL, stream>>>(x, nullptr, Wlin, blin,
                                                          Wc, bc, msgH, bufH);
    agg_kernel<<<AB, 256, 0, stream>>>(msgH, offsets, srcSorted, t, Wproj, bproj, bufH);
    // layer 1 (combine in place; f16 input)
    lin_kernel<true, false><<<LB, 256, LDS_DUAL, stream>>>(nullptr, bufH, Wlin + 4096,
                                                           blin + 64, Wc + 4096, bc + 64,
                                                           msgH, bufH);
    agg_kernel<<<AB, 256, 0, stream>>>(msgH, offsets, srcSorted, t + 64, Wproj + 5,
                                       bproj + 1, bufH);
    // global conv message (f16 input)
    lin_kernel<false, false><<<LB, 256, LDS_SINGLE, stream>>>(nullptr, bufH, gWlin,
                                                              gblin, nullptr, nullptr,
                                                              msgH, nullptr);
    gaggA_kernel<<<G_GRAPHS * GCH, 256, 0, stream>>>(msgH, gstart, pmn, pmx, psm);
    gaggB_kernel<<<G_GRAPHS, 64, 0, stream>>>(pmn, pmx, psm, gt, gMn, gMx, gSm, gBias);
    gaggC_kernel<<<G_GRAPHS * GCH, 256, 0, stream>>>(msgH, gstart, gBias, prs);
    gaggD_kernel<<<G_GRAPHS, 64, 0, stream>>>(prs, gstart, gMn, gMx, gSm, gWproj,
                                              gbproj, Wout, bout, out);
}

// Round 27
// 236.998 us; speedup vs baseline: 1.0143x; 1.0143x over previous
//
#include <hip/hip_runtime.h>
#include <hip/hip_fp16.h>

#define N_NODES 100000
#define E_EDGES 1600000
#define FDIM 64
#define G_GRAPHS 128
#define OUTD 32
#define NPB 512       // nodes per bucket (power of 2)
#define NPB_SH 9
#define KBUK ((N_NODES + NPB - 1) / NPB)   // 196 (<= 256)
#define CAPB 10240    // fixed edge capacity per bucket region
#define SEB 4096      // edges per block in bucket scatter
#define SEBLK ((E_EDGES + SEB - 1) / SEB)  // 391
#define GCH 16        // chunks per graph in global pooling

__device__ __forceinline__ __half2 u2h(unsigned int u) {
    union { unsigned int i; __half2 h; } c; c.i = u; return c.h;
}
__device__ __forceinline__ unsigned int h2u(__half2 h) {
    union { __half2 h; unsigned int i; } c; c.h = h; return c.i;
}
__device__ __forceinline__ __half2 sxh2(__half2 v, int off) {
    return u2h((unsigned int)__shfl_xor((int)h2u(v), off));
}
// packed f16 ops via VOP3P inline asm (ROCm fp16 header lacks __half2 min/max)
__device__ __forceinline__ __half2 h2min(__half2 a, __half2 b) {
    unsigned int r, x = h2u(a), y = h2u(b);
    asm("v_pk_min_f16 %0, %1, %2" : "=v"(r) : "v"(x), "v"(y));
    return u2h(r);
}
__device__ __forceinline__ __half2 h2max(__half2 a, __half2 b) {
    unsigned int r, x = h2u(a), y = h2u(b);
    asm("v_pk_max_f16 %0, %1, %2" : "=v"(r) : "v"(x), "v"(y));
    return u2h(r);
}
__device__ __forceinline__ __half2 h2add(__half2 a, __half2 b) {
    unsigned int r, x = h2u(a), y = h2u(b);
    asm("v_pk_add_f16 %0, %1, %2" : "=v"(r) : "v"(x), "v"(y));
    return u2h(r);
}
// f32 += f16x2 . f16x2 (packed dot product, f32 accumulate)
__device__ __forceinline__ float dot2(float acc, unsigned int a, unsigned int b) {
    float r;
    asm("v_dot2_f32_f16 %0, %1, %2, %3" : "=v"(r) : "v"(a), "v"(b), "v"(acc));
    return r;
}

// ---------------- CSR build (bucketed, fixed-capacity regions) ----------------

// batch is sorted -> graph starts at value changes; also init bucket cursors.
__global__ __launch_bounds__(256) void bound_kernel(const int* __restrict__ batch,
                                                    int* __restrict__ gstart,
                                                    int* __restrict__ bucketCursor) {
    int i = blockIdx.x * 256 + threadIdx.x;
    if (blockIdx.x == 0 && threadIdx.x < KBUK)
        bucketCursor[threadIdx.x * 16] = threadIdx.x * CAPB;
    if (i >= N_NODES) return;
    if (i == 0) {
        gstart[batch[0]] = 0;
    } else {
        int b = batch[i], pb = batch[i - 1];
        if (b != pb) gstart[b] = i;
    }
}

__global__ __launch_bounds__(256) void bscatter_kernel(const int* __restrict__ src,
                                                       const int* __restrict__ dst,
                                                       int* __restrict__ bucketCursor,
                                                       int* __restrict__ ebuf) {
    __shared__ int h[KBUK], resbase[KBUK], lcur[KBUK];
    for (int i = threadIdx.x; i < KBUK; i += 256) { h[i] = 0; lcur[i] = 0; }
    __syncthreads();
    const int base = blockIdx.x * SEB;
#pragma unroll
    for (int i = 0; i < 16; ++i) {
        int e = base + i * 256 + threadIdx.x;
        if (e < E_EDGES) atomicAdd(&h[dst[e] >> NPB_SH], 1);
    }
    __syncthreads();
    for (int i = threadIdx.x; i < KBUK; i += 256)
        resbase[i] = h[i] ? atomicAdd(&bucketCursor[i * 16], h[i]) : 0;
    __syncthreads();
#pragma unroll
    for (int i = 0; i < 16; ++i) {
        int e = base + i * 256 + threadIdx.x;
        if (e < E_EDGES) {
            int d = dst[e];
            int b = d >> NPB_SH;
            int pos = resbase[b] + atomicAdd(&lcur[b], 1);
            ebuf[pos] = (src[e] << NPB_SH) | (d & (NPB - 1));
        }
    }
}

__global__ __launch_bounds__(256) void bscan_kernel(const int* __restrict__ bucketCursor,
                                                    int* __restrict__ bucketStart,
                                                    int* __restrict__ offsets) {
    __shared__ int s[256];
    const int tid = threadIdx.x;
    int v = (tid < KBUK) ? (bucketCursor[tid * 16] - tid * CAPB) : 0;
    s[tid] = v;
    __syncthreads();
    for (int off = 1; off < 256; off <<= 1) {
        int t = 0;
        if (tid >= off) t = s[tid - off];
        __syncthreads();
        if (tid >= off) s[tid] += t;
        __syncthreads();
    }
    int excl = s[tid] - v;
    if (tid < KBUK) bucketStart[tid] = excl;
    if (tid == 0) { bucketStart[KBUK] = E_EDGES; offsets[N_NODES] = E_EDGES; }
}

// per-bucket counting sort -> offsets[] + srcSorted[] (prescaled by 16 = uint2-row)
__global__ __launch_bounds__(256) void bsort_kernel(const int* __restrict__ ebuf,
                                                    const int* __restrict__ bucketStart,
                                                    int* __restrict__ offsets,
                                                    int* __restrict__ srcSorted) {
    __shared__ int cnt[NPB];
    __shared__ int cur[NPB];
    __shared__ int wsum[4];
    const int b = blockIdx.x;
    const int tid = threadIdx.x;
    const int rbase = b * CAPB;
    const int ebase = bucketStart[b];
    const int cb = bucketStart[b + 1] - ebase;
    const int nbase = b * NPB;
    cnt[tid] = 0; cnt[tid + 256] = 0;
    __syncthreads();
    for (int e = tid; e < cb; e += 256)
        atomicAdd(&cnt[ebuf[rbase + e] & (NPB - 1)], 1);
    __syncthreads();
    int v0 = cnt[2 * tid], v1 = cnt[2 * tid + 1];
    int s = v0 + v1;
    const int lane = tid & 63, wv = tid >> 6;
    int incl = s;
#pragma unroll
    for (int off = 1; off < 64; off <<= 1) {
        int o = __shfl_up(incl, off);
        if (lane >= off) incl += o;
    }
    if (lane == 63) wsum[wv] = incl;
    __syncthreads();
    int wpre = 0;
#pragma unroll
    for (int w = 0; w < 4; ++w) wpre += (w < wv) ? wsum[w] : 0;
    int excl = wpre + incl - s;
    cur[2 * tid] = excl; cur[2 * tid + 1] = excl + v0;
    int n0 = nbase + 2 * tid;
    if (n0 < N_NODES) offsets[n0] = ebase + excl;
    if (n0 + 1 < N_NODES) offsets[n0 + 1] = ebase + excl + v0;
    __syncthreads();
    for (int e = tid; e < cb; e += 256) {
        int u = ebuf[rbase + e];
        int pos = ebase + atomicAdd(&cur[u & (NPB - 1)], 1);
        srcSorted[pos] = (u >> NPB_SH) << 4;  // prescaled row offset (uint2 units)
    }
}

// ---------------- linear (4x4 register-tiled, dot2, optional dual W) ----------------
// 256 threads = 16 node-quads x 16 feature-quads; block = 64 nodes.
// h AND W tiles in LDS as f16; inner loop = chained v_dot2_f32_f16.
// #pragma unroll 1 caps register pressure (round-10 spill lesson).
// In-place safe (outC == in): block stages its own rows before the barrier.

template <bool DUAL>
__global__ __launch_bounds__(256) void lin_kernel(const float* __restrict__ in,
                                                  const float* __restrict__ Wm,
                                                  const float* __restrict__ bm,
                                                  const float* __restrict__ Wc,
                                                  const float* __restrict__ bc,
                                                  __half* __restrict__ outMsg,
                                                  float* __restrict__ outC) {
    extern __shared__ uint2 shu[];
    uint2* shH  = shu;          // 1024
    uint2* shWm = shu + 1024;   // 1024
    uint2* shWc = shu + 2048;   // dual only
    const int tid = threadIdx.x;
    const int base = blockIdx.x * 64;
#pragma unroll
    for (int i = 0; i < 4; ++i) {
        int j = tid + i * 256;                 // 4-elem unit index in 64x64 tile
        int row = j >> 4, col = j & 15;
        int swz = row * 16 + (col ^ ((row >> 2) & 7));
        if (base + row < N_NODES) {
            float4 hv = ((const float4*)in)[(size_t)base * 16 + j];
            uint2 ph;
            ph.x = h2u(__floats2half2_rn(hv.x, hv.y));
            ph.y = h2u(__floats2half2_rn(hv.z, hv.w));
            shH[swz] = ph;
        }
        float4 wm = ((const float4*)Wm)[j];
        uint2 pm;
        pm.x = h2u(__floats2half2_rn(wm.x, wm.y));
        pm.y = h2u(__floats2half2_rn(wm.z, wm.w));
        shWm[swz] = pm;
        if (DUAL) {
            float4 wc = ((const float4*)Wc)[j];
            uint2 pc;
            pc.x = h2u(__floats2half2_rn(wc.x, wc.y));
            pc.y = h2u(__floats2half2_rn(wc.z, wc.w));
            shWc[swz] = pc;
        }
    }
    __syncthreads();
    const int fj = tid & 15, ni = tid >> 4;
    float accM[4][4] = {{0}}, accC[4][4] = {{0}};
    const int hs = ni & 7;
    const int ws = fj & 7;
#pragma unroll 1
    for (int kk = 0; kk < 16; ++kk) {
        const int hk = kk ^ hs, wk = kk ^ ws;
        uint2 h0 = shH[(4 * ni + 0) * 16 + hk];
        uint2 h1 = shH[(4 * ni + 1) * 16 + hk];
        uint2 h2 = shH[(4 * ni + 2) * 16 + hk];
        uint2 h3 = shH[(4 * ni + 3) * 16 + hk];
#pragma unroll
        for (int j = 0; j < 4; ++j) {
            uint2 wu = shWm[(4 * fj + j) * 16 + wk];
            accM[0][j] = dot2(dot2(accM[0][j], h0.x, wu.x), h0.y, wu.y);
            accM[1][j] = dot2(dot2(accM[1][j], h1.x, wu.x), h1.y, wu.y);
            accM[2][j] = dot2(dot2(accM[2][j], h2.x, wu.x), h2.y, wu.y);
            accM[3][j] = dot2(dot2(accM[3][j], h3.x, wu.x), h3.y, wu.y);
            if (DUAL) {
                uint2 cu = shWc[(4 * fj + j) * 16 + wk];
                accC[0][j] = dot2(dot2(accC[0][j], h0.x, cu.x), h0.y, cu.y);
                accC[1][j] = dot2(dot2(accC[1][j], h1.x, cu.x), h1.y, cu.y);
                accC[2][j] = dot2(dot2(accC[2][j], h2.x, cu.x), h2.y, cu.y);
                accC[3][j] = dot2(dot2(accC[3][j], h3.x, cu.x), h3.y, cu.y);
            }
        }
    }
    float4 bm4 = *(const float4*)(bm + 4 * fj);
    float4 bc4 = DUAL ? *(const float4*)(bc + 4 * fj) : make_float4(0, 0, 0, 0);
#pragma unroll
    for (int r = 0; r < 4; ++r) {
        int node = base + 4 * ni + r;
        if (node < N_NODES) {
            uint2 st;
            st.x = h2u(__floats2half2_rn(accM[r][0] + bm4.x, accM[r][1] + bm4.y));
            st.y = h2u(__floats2half2_rn(accM[r][2] + bm4.z, accM[r][3] + bm4.w));
            *(uint2*)(outMsg + (size_t)node * 64 + 4 * fj) = st;
            if (DUAL) {
                float4 c = make_float4(accC[r][0] + bc4.x, accC[r][1] + bc4.y,
                                       accC[r][2] + bc4.z, accC[r][3] + bc4.w);
                *(float4*)(outC + (size_t)node * 64 + 4 * fj) = c;
            }
        }
    }
}

// ---------------- per-node adaptive-relu aggregation (register-held, no LDS) ----
// wave per node; lane = (edge group g = lane>>4, feature quad fq = lane&15).
// deg>=16: ALL 8 gathers issued before any stat op (round-24 MLP lesson).

__global__ __launch_bounds__(256) void agg_kernel(const __half* __restrict__ msgH,
                                                  const int* __restrict__ offsets,
                                                  const int* __restrict__ srcSorted,
                                                  const float* __restrict__ tptr,
                                                  const float* __restrict__ Wp,
                                                  const float* __restrict__ bp,
                                                  float* __restrict__ hbuf) {
    const int lane = threadIdx.x & 63;
    const int g = lane >> 4;
    const int fq = lane & 15;
    const int node = blockIdx.x * 4 + (threadIdx.x >> 6);
    if (node >= N_NODES) return;
    const int start = offsets[node], end = offsets[node + 1];
    const int deg = end - start;
    const uint2* mq = (const uint2*)msgH + fq;  // row stride = 16 uint2 (128 B)
    const float INF = 65504.f;  // f16 max
    __half2 mnA = __float2half2_rn(INF),  mnB = __float2half2_rn(INF);
    __half2 mxA = __float2half2_rn(-INF), mxB = __float2half2_rn(-INF);
    __half2 smA = __float2half2_rn(0.f),  smB = __float2half2_rn(0.f);

#define ACCU(u) { __half2 a_ = u2h((u).x), b_ = u2h((u).y); \
    mnA = h2min(mnA, a_); mxA = h2max(mxA, a_); smA = h2add(smA, a_); \
    mnB = h2min(mnB, b_); mxB = h2max(mxB, b_); smB = h2add(smB, b_); }

    // register-held first 32 slots
    uint2 u0, u1, u2, u3, v0, v1, v2, v3;
    bool okU0 = false, okU1 = false, okU2 = false, okU3 = false;
    bool okV0 = false, okV1 = false, okV2 = false, okV3 = false;

    if (deg >= 16) {
        // ---- issue ALL loads first (8 gathers in flight) ----
        int i0 = start + g;
        int s0 = srcSorted[i0], s1 = srcSorted[i0 + 4];
        int s2 = srcSorted[i0 + 8], s3 = srcSorted[i0 + 12];
        u0 = mq[(size_t)s0]; u1 = mq[(size_t)s1];
        u2 = mq[(size_t)s2]; u3 = mq[(size_t)s3];
        okU0 = okU1 = okU2 = okU3 = true;
        int j0 = start + 16 + g, j1 = j0 + 4, j2 = j0 + 8, j3 = j0 + 12;
        okV0 = j0 < end; okV1 = j1 < end; okV2 = j2 < end; okV3 = j3 < end;
        int t0 = 0, t1 = 0, t2 = 0, t3 = 0;
        if (okV0) t0 = srcSorted[j0];
        if (okV1) t1 = srcSorted[j1];
        if (okV2) t2 = srcSorted[j2];
        if (okV3) t3 = srcSorted[j3];
        if (okV0) v0 = mq[(size_t)t0];
        if (okV1) v1 = mq[(size_t)t1];
        if (okV2) v2 = mq[(size_t)t2];
        if (okV3) v3 = mq[(size_t)t3];
        // ---- then drain into stats ----
        ACCU(u0) ACCU(u1) ACCU(u2) ACCU(u3)
        if (okV0) ACCU(v0)
        if (okV1) ACCU(v1)
        if (okV2) ACCU(v2)
        if (okV3) ACCU(v3)
        if (deg > 32) {   // overflow: stats only (re-gathered in pass 2)
            for (int e = start + 32; e < end; e += 16) {
                int i0e = e + g, i1e = i0e + 4, i2e = i0e + 8, i3e = i0e + 12;
                bool ok0 = i0e < end, ok1 = i1e < end, ok2 = i2e < end, ok3 = i3e < end;
                int s0e = 0, s1e = 0, s2e = 0, s3e = 0;
                if (ok0) s0e = srcSorted[i0e];
                if (ok1) s1e = srcSorted[i1e];
                if (ok2) s2e = srcSorted[i2e];
                if (ok3) s3e = srcSorted[i3e];
                uint2 w0, w1, w2, w3;
                if (ok0) w0 = mq[(size_t)s0e];
                if (ok1) w1 = mq[(size_t)s1e];
                if (ok2) w2 = mq[(size_t)s2e];
                if (ok3) w3 = mq[(size_t)s3e];
                if (ok0) ACCU(w0)
                if (ok1) ACCU(w1)
                if (ok2) ACCU(w2)
                if (ok3) ACCU(w3)
            }
        }
    } else {   // deg < 16: single masked load
        int i0 = start + g, i1 = i0 + 4, i2 = i0 + 8, i3 = i0 + 12;
        okU0 = i0 < end; okU1 = i1 < end; okU2 = i2 < end; okU3 = i3 < end;
        int s0 = 0, s1 = 0, s2 = 0, s3 = 0;
        if (okU0) s0 = srcSorted[i0];
        if (okU1) s1 = srcSorted[i1];
        if (okU2) s2 = srcSorted[i2];
        if (okU3) s3 = srcSorted[i3];
        if (okU0) u0 = mq[(size_t)s0];
        if (okU1) u1 = mq[(size_t)s1];
        if (okU2) u2 = mq[(size_t)s2];
        if (okU3) u3 = mq[(size_t)s3];
        if (okU0) ACCU(u0)
        if (okU1) ACCU(u1)
        if (okU2) ACCU(u2)
        if (okU3) ACCU(u3)
    }
#pragma unroll
    for (int off = 16; off <= 32; off <<= 1) {
        mnA = h2min(mnA, sxh2(mnA, off)); mnB = h2min(mnB, sxh2(mnB, off));
        mxA = h2max(mxA, sxh2(mxA, off)); mxB = h2max(mxB, sxh2(mxB, off));
        smA = h2add(smA, sxh2(smA, off)); smB = h2add(smB, sxh2(smB, off));
    }
    float mn0 = __low2float(mnA), mn1 = __high2float(mnA);
    float mn2 = __low2float(mnB), mn3 = __high2float(mnB);
    float mx0 = __low2float(mxA), mx1 = __high2float(mxA);
    float mx2 = __low2float(mxB), mx3 = __high2float(mxB);
    float4 tv = *(const float4*)(tptr + 4 * fq);
    tv.x = fminf(fmaxf(tv.x, 0.f), 1.f); tv.y = fminf(fmaxf(tv.y, 0.f), 1.f);
    tv.z = fminf(fmaxf(tv.z, 0.f), 1.f); tv.w = fminf(fmaxf(tv.w, 0.f), 1.f);
    float b0 = tv.x * mx0 + (1.f - tv.x) * mn0;
    float b1 = tv.y * mx1 + (1.f - tv.y) * mn1;
    float b2 = tv.z * mx2 + (1.f - tv.z) * mn2;
    float b3 = tv.w * mx3 + (1.f - tv.w) * mn3;
    __half2 biasA = __floats2half2_rn(b0, b1);
    __half2 biasB = __floats2half2_rn(b2, b3);
    float fb0 = __low2float(biasA), fb1 = __high2float(biasA);
    float fb2 = __low2float(biasB), fb3 = __high2float(biasB);
    __half2 rsA = __float2half2_rn(0.f), rsB = __float2half2_rn(0.f);

#define RACCU(u) { __half2 a_ = u2h((u).x), b_ = u2h((u).y); \
    rsA = h2add(rsA, h2max(a_, biasA)); \
    rsB = h2add(rsB, h2max(b_, biasB)); }

    // pass 2: from registers (flags mirror pass 1)
    if (okU0) RACCU(u0)
    if (okU1) RACCU(u1)
    if (okU2) RACCU(u2)
    if (okU3) RACCU(u3)
    if (okV0) RACCU(v0)
    if (okV1) RACCU(v1)
    if (okV2) RACCU(v2)
    if (okV3) RACCU(v3)
    if (deg > 32) {   // rare overflow: re-gather
        for (int e = start + 32; e < end; e += 16) {
            int i0e = e + g, i1e = i0e + 4, i2e = i0e + 8, i3e = i0e + 12;
            bool ok0 = i0e < end, ok1 = i1e < end, ok2 = i2e < end, ok3 = i3e < end;
            int s0e = 0, s1e = 0, s2e = 0, s3e = 0;
            if (ok0) s0e = srcSorted[i0e];
            if (ok1) s1e = srcSorted[i1e];
            if (ok2) s2e = srcSorted[i2e];
            if (ok3) s3e = srcSorted[i3e];
            uint2 w0, w1, w2, w3;
            if (ok0) w0 = mq[(size_t)s0e];
            if (ok1) w1 = mq[(size_t)s1e];
            if (ok2) w2 = mq[(size_t)s2e];
            if (ok3) w3 = mq[(size_t)s3e];
            if (ok0) RACCU(w0)
            if (ok1) RACCU(w1)
            if (ok2) RACCU(w2)
            if (ok3) RACCU(w3)
        }
    }
#pragma unroll
    for (int off = 16; off <= 32; off <<= 1) {
        rsA = h2add(rsA, sxh2(rsA, off));
        rsB = h2add(rsB, sxh2(rsB, off));
    }
    if (g == 0) {
        float cnt = (float)deg;
        float w0 = Wp[0], w1 = Wp[1], w2 = Wp[2], w3 = Wp[3], w4 = Wp[4], bp0 = bp[0];
        float rs0 = __low2float(rsA) - cnt * fb0;
        float rs1 = __high2float(rsA) - cnt * fb1;
        float rs2 = __low2float(rsB) - cnt * fb2;
        float rs3 = __high2float(rsB) - cnt * fb3;
        float sm0 = __low2float(smA), sm1 = __high2float(smA);
        float sm2 = __low2float(smB), sm3 = __high2float(smB);
        float4* hp = (float4*)(hbuf + (size_t)node * 64 + 4 * fq);
        float4 h = *hp;
        h.x += w0 * cnt + w1 * mn0 + w2 * mx0 + w3 * rs0 + w4 * sm0 + bp0;
        h.y += w0 * cnt + w1 * mn1 + w2 * mx1 + w3 * rs1 + w4 * sm1 + bp0;
        h.z += w0 * cnt + w1 * mn2 + w2 * mx2 + w3 * rs2 + w4 * sm2 + bp0;
        h.w += w0 * cnt + w1 * mn3 + w2 * mx3 + w3 * rs3 + w4 * sm3 + bp0;
        *hp = h;
    }
#undef ACCU
#undef RACCU
}

// ---------------- global pooling (4-phase; vectorized __half2 loads) ----------

// A: partial min/max/sum; lane = (feature pair p = tid&31, row-walker r = tid>>5)
__global__ __launch_bounds__(256) void gaggA_kernel(const __half* __restrict__ msgH,
                                                    const int* __restrict__ gstart,
                                                    float* __restrict__ pmn,
                                                    float* __restrict__ pmx,
                                                    float* __restrict__ psm) {
    const int bid = blockIdx.x;
    const int g = bid >> 4, c = bid & (GCH - 1);
    const int s = gstart[g];
    const int e = (g == G_GRAPHS - 1) ? N_NODES : gstart[g + 1];
    const int clen = (e - s + GCH - 1) / GCH;
    const int cs = s + c * clen;
    const int ce = (cs + clen < e) ? (cs + clen) : e;
    const int p = threadIdx.x & 31, r = threadIdx.x >> 5;
    const float INF = __builtin_inff();
    float mn0 = INF, mn1 = INF, mx0 = -INF, mx1 = -INF, sm0 = 0.f, sm1 = 0.f;
    for (int i = cs + r; i < ce; i += 8) {
        unsigned int u = *(const unsigned int*)(msgH + (size_t)i * 64 + 2 * p);
        __half2 h = u2h(u);
        float v0 = __low2float(h), v1 = __high2float(h);
        mn0 = fminf(mn0, v0); mx0 = fmaxf(mx0, v0); sm0 += v0;
        mn1 = fminf(mn1, v1); mx1 = fmaxf(mx1, v1); sm1 += v1;
    }
    __shared__ float smn[8][64], smx[8][64], ssm[8][64];
    smn[r][2 * p] = mn0; smn[r][2 * p + 1] = mn1;
    smx[r][2 * p] = mx0; smx[r][2 * p + 1] = mx1;
    ssm[r][2 * p] = sm0; ssm[r][2 * p + 1] = sm1;
    __syncthreads();
    if (threadIdx.x < 64) {
        int f = threadIdx.x;
        float mn = smn[0][f], mx = smx[0][f], sm = ssm[0][f];
#pragma unroll
        for (int k = 1; k < 8; ++k) {
            mn = fminf(mn, smn[k][f]); mx = fmaxf(mx, smx[k][f]); sm += ssm[k][f];
        }
        pmn[bid * 64 + f] = mn; pmx[bid * 64 + f] = mx; psm[bid * 64 + f] = sm;
    }
}

__global__ __launch_bounds__(64) void gaggB_kernel(const float* __restrict__ pmn,
                                                   const float* __restrict__ pmx,
                                                   const float* __restrict__ psm,
                                                   const float* __restrict__ gt,
                                                   float* __restrict__ gMn,
                                                   float* __restrict__ gMx,
                                                   float* __restrict__ gSm,
                                                   float* __restrict__ gBias) {
    const int g = blockIdx.x, f = threadIdx.x;
    float mn = __builtin_inff(), mx = -__builtin_inff(), sm = 0.f;
#pragma unroll
    for (int c = 0; c < GCH; ++c) {
        int i = (g * GCH + c) * 64 + f;
        mn = fminf(mn, pmn[i]); mx = fmaxf(mx, pmx[i]); sm += psm[i];
    }
    float tv = fminf(fmaxf(gt[f], 0.f), 1.f);
    gMn[g * 64 + f] = mn; gMx[g * 64 + f] = mx; gSm[g * 64 + f] = sm;
    gBias[g * 64 + f] = tv * mx + (1.f - tv) * mn;
}

// C: partial relu sums (vectorized __half2 loads)
__global__ __launch_bounds__(256) void gaggC_kernel(const __half* __restrict__ msgH,
                                                    const int* __restrict__ gstart,
                                                    const float* __restrict__ gBias,
                                                    float* __restrict__ prs) {
    const int bid = blockIdx.x;
    const int g = bid >> 4, c = bid & (GCH - 1);
    const int s = gstart[g];
    const int e = (g == G_GRAPHS - 1) ? N_NODES : gstart[g + 1];
    const int clen = (e - s + GCH - 1) / GCH;
    const int cs = s + c * clen;
    const int ce = (cs + clen < e) ? (cs + clen) : e;
    const int p = threadIdx.x & 31, r = threadIdx.x >> 5;
    const float bias0 = gBias[g * 64 + 2 * p];
    const float bias1 = gBias[g * 64 + 2 * p + 1];
    float rs0 = 0.f, rs1 = 0.f;
    for (int i = cs + r; i < ce; i += 8) {
        unsigned int u = *(const unsigned int*)(msgH + (size_t)i * 64 + 2 * p);
        __half2 h = u2h(u);
        rs0 += fmaxf(__low2float(h) - bias0, 0.f);
        rs1 += fmaxf(__high2float(h) - bias1, 0.f);
    }
    __shared__ float srs[8][64];
    srs[r][2 * p] = rs0; srs[r][2 * p + 1] = rs1;
    __syncthreads();
    if (threadIdx.x < 64) {
        int f = threadIdx.x;
        float rs = srs[0][f];
#pragma unroll
        for (int k = 1; k < 8; ++k) rs += srs[k][f];
        prs[bid * 64 + f] = rs;
    }
}

__global__ __launch_bounds__(64) void gaggD_kernel(const float* __restrict__ prs,
                                                   const int* __restrict__ gstart,
                                                   const float* __restrict__ gMn,
                                                   const float* __restrict__ gMx,
                                                   const float* __restrict__ gSm,
                                                   const float* __restrict__ gWp,
                                                   const float* __restrict__ gbp,
                                                   const float* __restrict__ Wout,
                                                   const float* __restrict__ bout,
                                                   float* __restrict__ out) {
    const int g = blockIdx.x, f = threadIdx.x;
    float rs = 0.f;
#pragma unroll
    for (int c = 0; c < GCH; ++c) rs += prs[(g * GCH + c) * 64 + f];
    const int s = gstart[g];
    const int e = (g == G_GRAPHS - 1) ? N_NODES : gstart[g + 1];
    float cnt = (float)(e - s);
    __shared__ float emb[64];
    emb[f] = gWp[0] * cnt + gWp[1] * gMn[g * 64 + f] + gWp[2] * gMx[g * 64 + f] +
             gWp[3] * rs + gWp[4] * gSm[g * 64 + f] + gbp[0];
    __syncthreads();
    if (f < OUTD) {
        float a = bout[f];
        const float* wr = Wout + f * 64;
#pragma unroll
        for (int k = 0; k < 64; ++k) a = fmaf(emb[k], wr[k], a);
        out[g * OUTD + f] = a;
    }
}

// ---------------- launch ----------------

extern "C" void kernel_launch(void* const* d_in, const int* in_sizes, int n_in,
                              void* d_out, int out_size, void* d_ws, size_t ws_size,
                              hipStream_t stream) {
    const float* x     = (const float*)d_in[0];
    const int*   ei    = (const int*)d_in[1];
    const int*   batch = (const int*)d_in[2];
    const float* Wlin  = (const float*)d_in[3];
    const float* blin  = (const float*)d_in[4];
    const float* t     = (const float*)d_in[5];
    const float* Wproj = (const float*)d_in[6];
    const float* bproj = (const float*)d_in[7];
    const float* Wc    = (const float*)d_in[8];
    const float* bc    = (const float*)d_in[9];
    const float* gWlin = (const float*)d_in[10];
    const float* gblin = (const float*)d_in[11];
    const float* gt    = (const float*)d_in[12];
    const float* gWproj= (const float*)d_in[13];
    const float* gbproj= (const float*)d_in[14];
    const float* Wout  = (const float*)d_in[15];
    const float* bout  = (const float*)d_in[16];
    float* out = (float*)d_out;

    const int* src = ei;
    const int* dst = ei + E_EDGES;

    // workspace layout
    char* p = (char*)d_ws;
    float* bufH   = (float*)p; p += (size_t)N_NODES * FDIM * sizeof(float);
    __half* msgH  = (__half*)p; p += (size_t)N_NODES * FDIM * sizeof(__half);
    int* ebuf     = (int*)p;   p += (size_t)KBUK * CAPB * sizeof(int);
    int* offsets  = (int*)p;   p += (size_t)(N_NODES + 1) * sizeof(int);
    int* gstart   = (int*)p;   p += (size_t)G_GRAPHS * sizeof(int);
    int* bucketStart  = (int*)p; p += (size_t)(KBUK + 1) * sizeof(int);
    int* bucketCursor = (int*)p; p += (size_t)KBUK * 16 * sizeof(int);
    int* srcSorted= (int*)p;   p += (size_t)E_EDGES * sizeof(int);
    float* pmn = (float*)p;    p += (size_t)G_GRAPHS * GCH * 64 * sizeof(float);
    float* pmx = (float*)p;    p += (size_t)G_GRAPHS * GCH * 64 * sizeof(float);
    float* psm = (float*)p;    p += (size_t)G_GRAPHS * GCH * 64 * sizeof(float);
    float* prs = (float*)p;    p += (size_t)G_GRAPHS * GCH * 64 * sizeof(float);
    float* gMn = (float*)p;    p += (size_t)G_GRAPHS * 64 * sizeof(float);
    float* gMx = (float*)p;    p += (size_t)G_GRAPHS * 64 * sizeof(float);
    float* gSm = (float*)p;    p += (size_t)G_GRAPHS * 64 * sizeof(float);
    float* gBias = (float*)p;  p += (size_t)G_GRAPHS * 64 * sizeof(float);

    const int NB = (N_NODES + 255) / 256;
    bound_kernel<<<NB, 256, 0, stream>>>(batch, gstart, bucketCursor);
    bscatter_kernel<<<SEBLK, 256, 0, stream>>>(src, dst, bucketCursor, ebuf);
    bscan_kernel<<<1, 256, 0, stream>>>(bucketCursor, bucketStart, offsets);
    bsort_kernel<<<KBUK, 256, 0, stream>>>(ebuf, bucketStart, offsets, srcSorted);

    const int LB = (N_NODES + 63) / 64;
    const int AB = (N_NODES + 3) / 4;
    const size_t LDS_DUAL = 3 * 1024 * sizeof(uint2);    // 24 KB
    const size_t LDS_SINGLE = 2 * 1024 * sizeof(uint2);  // 16 KB

    // layer 0: msg (f16) + combine (f32) fused, from x
    lin_kernel<true><<<LB, 256, LDS_DUAL, stream>>>(x, Wlin, blin, Wc, bc, msgH, bufH);
    agg_kernel<<<AB, 256, 0, stream>>>(msgH, offsets, srcSorted, t, Wproj, bproj, bufH);
    // layer 1 (combine in place)
    lin_kernel<true><<<LB, 256, LDS_DUAL, stream>>>(bufH, Wlin + 4096, blin + 64,
                                                    Wc + 4096, bc + 64, msgH, bufH);
    agg_kernel<<<AB, 256, 0, stream>>>(msgH, offsets, srcSorted, t + 64, Wproj + 5,
                                       bproj + 1, bufH);
    // global conv message (f16)
    lin_kernel<false><<<LB, 256, LDS_SINGLE, stream>>>(bufH, gWlin, gblin, nullptr,
                                                       nullptr, msgH, nullptr);
    gaggA_kernel<<<G_GRAPHS * GCH, 256, 0, stream>>>(msgH, gstart, pmn, pmx, psm);
    gaggB_kernel<<<G_GRAPHS, 64, 0, stream>>>(pmn, pmx, psm, gt, gMn, gMx, gSm, gBias);
    gaggC_kernel<<<G_GRAPHS * GCH, 256, 0, stream>>>(msgH, gstart, gBias, prs);
    gaggD_kernel<<<G_GRAPHS, 64, 0, stream>>>(prs, gstart, gMn, gMx, gSm, gWproj,
                                              gbproj, Wout, bout, out);
}